// Round 3
// baseline (38.973 us; speedup 1.0000x reference)
//
#include <hip/hip_runtime.h>
#include <math.h>

// Problem constants (match reference)
#define BB 8
#define DD 3
#define NN 4096
#define LATENT 256

#define Q 8                         // queries per thread (ILP + LDS amortization)
#define THREADS 256
#define QB (Q * THREADS)            // 2048 queries per block
#define QTILES (NN / QB)            // 2
#define BLOCKS_X (2 * BB * QTILES)  // 32  (dir x batch x qtile)
#define TOTQ (2 * BB * NN)          // 65536 total (dir,b,n) query slots

// ---------------------------------------------------------------------------
// Stage 1: block (bx, c) = (dir,b,qtile) x candidate-tile c.
// Stages T = NN/C candidates into dynamic LDS as {-2y0,-2y1,-2y2,|y|^2};
// each thread scans the tile for its 8 query points (8 independent min
// chains), 2 candidates per update so nested fmin fuses to v_min3_f32.
// Per 2 pairs: 6 FMA + 1 min3. Writes sx + tile-min to partial.
// ---------------------------------------------------------------------------
__global__ __launch_bounds__(THREADS)
void chamfer_stage1(const float* __restrict__ recon,
                    const float* __restrict__ x,
                    float* __restrict__ partial,
                    int C, int T)
{
    extern __shared__ float4 ly[];   // T * 16 bytes

    const int bx  = blockIdx.x;      // 0..31
    const int c   = blockIdx.y;      // 0..C-1
    const int dir = bx >> 4;
    const int rem = bx & 15;
    const int b   = rem >> 1;
    const int qt  = rem & 1;
    const int tid = threadIdx.x;

    const float* cloud = (dir ? recon : x) + (size_t)b * DD * NN;
    const float* query = (dir ? x : recon) + (size_t)b * DD * NN;

    // Stage this block's candidate tile (pre-scaled) into LDS
    for (int i = tid; i < T; i += THREADS) {
        int m = c * T + i;
        float y0 = cloud[0 * NN + m];
        float y1 = cloud[1 * NN + m];
        float y2 = cloud[2 * NN + m];
        ly[i] = make_float4(-2.0f * y0, -2.0f * y1, -2.0f * y2,
                            y0 * y0 + y1 * y1 + y2 * y2);
    }
    __syncthreads();

    float px[Q], py[Q], pz[Q], mn[Q];
    const int q0 = qt * QB + tid;
#pragma unroll
    for (int k = 0; k < Q; ++k) {
        int q = q0 + k * THREADS;
        px[k] = query[0 * NN + q];
        py[k] = query[1 * NN + q];
        pz[k] = query[2 * NN + q];
        mn[k] = 3.4e38f;
    }

    // T is a multiple of 2 for all C in {1..64}
#pragma unroll 2
    for (int m = 0; m < T; m += 2) {
        float4 v0 = ly[m];           // broadcast ds_read_b128, serves 8 pairs
        float4 v1 = ly[m + 1];
#pragma unroll
        for (int k = 0; k < Q; ++k) {
            float t0 = fmaf(px[k], v0.x, fmaf(py[k], v0.y, fmaf(pz[k], v0.z, v0.w)));
            float t1 = fmaf(px[k], v1.x, fmaf(py[k], v1.y, fmaf(pz[k], v1.z, v1.w)));
            mn[k] = fminf(fminf(mn[k], t0), t1);   // -> v_min3_f32
        }
    }

    // partial[c][dir][b][n] : coalesced writes
    float* dst = partial + (size_t)c * TOTQ + (size_t)dir * (BB * NN) + b * NN + q0;
#pragma unroll
    for (int k = 0; k < Q; ++k) {
        float sx = px[k] * px[k] + py[k] * py[k] + pz[k] * pz[k];
        dst[k * THREADS] = sx + mn[k];
    }
}

// ---------------------------------------------------------------------------
// Stage 2: min across the C candidate tiles per query, then block-sum.
// 256 blocks x 256 threads, one query slot per thread.
// ---------------------------------------------------------------------------
__global__ __launch_bounds__(THREADS)
void chamfer_stage2(const float* __restrict__ partial,
                    float* __restrict__ sums, int C)
{
    __shared__ float red[4];
    const int tid = threadIdx.x;
    const int gq  = blockIdx.x * THREADS + tid;

    float m = partial[gq];
    for (int cc = 1; cc < C; ++cc)
        m = fminf(m, partial[(size_t)cc * TOTQ + gq]);

    for (int off = 32; off > 0; off >>= 1)
        m += __shfl_down(m, off);
    if ((tid & 63) == 0) red[tid >> 6] = m;
    __syncthreads();
    if (tid == 0)
        sums[blockIdx.x] = red[0] + red[1] + red[2] + red[3];
}

// ---------------------------------------------------------------------------
// Finalize: sum 256 block sums, compute KL over 8x256, write 3 outputs.
// ---------------------------------------------------------------------------
__global__ __launch_bounds__(THREADS)
void finalize_kernel(const float* __restrict__ sums,
                     const float* __restrict__ mu,
                     const float* __restrict__ logvar,
                     float* __restrict__ out)
{
    __shared__ float redA[4];
    __shared__ float redB[4];
    const int tid = threadIdx.x;

    float s = sums[tid];   // exactly 256 partial sums

    float kl = 0.0f;
    for (int i = tid; i < BB * LATENT; i += THREADS) {
        float m  = mu[i];
        float lv = logvar[i];
        kl += 1.0f + lv - m * m - expf(lv);
    }

    for (int off = 32; off > 0; off >>= 1) {
        s  += __shfl_down(s, off);
        kl += __shfl_down(kl, off);
    }
    if ((tid & 63) == 0) { redA[tid >> 6] = s; redB[tid >> 6] = kl; }
    __syncthreads();
    if (tid == 0) {
        float chamfer_sum = redA[0] + redA[1] + redA[2] + redA[3];
        float kl_sum      = redB[0] + redB[1] + redB[2] + redB[3];
        float recon = chamfer_sum / (float)(BB * NN);   // mean over both dirs
        float kld   = -0.5f * kl_sum / (float)BB;
        out[0] = recon + kld;
        out[1] = recon;
        out[2] = kld;
    }
}

extern "C" void kernel_launch(void* const* d_in, const int* in_sizes, int n_in,
                              void* d_out, int out_size, void* d_ws, size_t ws_size,
                              hipStream_t stream)
{
    const float* recon  = (const float*)d_in[0];
    const float* x      = (const float*)d_in[1];
    const float* mu     = (const float*)d_in[2];
    const float* logvar = (const float*)d_in[3];
    float* out = (float*)d_out;

    // Pick the largest candidate split C whose partial buffer fits d_ws.
    // C=32 -> 4 blocks/CU (4 waves/SIMD), partial = 8 MB.
    int C = 1;
    for (int c = 32; c >= 1; c >>= 1) {
        size_t need = (size_t)c * TOTQ * sizeof(float) + 256 * sizeof(float);
        if (need <= ws_size) { C = c; break; }
    }
    const int T = NN / C;

    float* partial = (float*)d_ws;                 // C * 65536 floats
    float* sums    = partial + (size_t)C * TOTQ;   // 256 floats

    dim3 g1(BLOCKS_X, C);
    size_t lds = (size_t)T * sizeof(float4);
    chamfer_stage1<<<g1, THREADS, lds, stream>>>(recon, x, partial, C, T);
    chamfer_stage2<<<256, THREADS, 0, stream>>>(partial, sums, C);
    finalize_kernel<<<1, THREADS, 0, stream>>>(sums, mu, logvar, out);
}